// Round 2
// baseline (1773.084 us; speedup 1.0000x reference)
//
#include <hip/hip_runtime.h>
#include <hip/hip_bf16.h>

#define E_EDGES 120000
#define NUM_NODES 12000

typedef __attribute__((ext_vector_type(8))) short bfrag;          // 8 bf16
typedef __attribute__((ext_vector_type(8))) unsigned short ushort8;
typedef __attribute__((ext_vector_type(4))) float f32x4;

#define INV_SQRT3 0.57735026918962576f
#define SQRT2_C   1.41421356237309515f
#define N_0E_C    0.14433756729740643f   /* 1/sqrt(48) */
#define NV_C      0.14433756729740643f   /* sqrt(3/48)*1/sqrt(3) = 1/sqrt(48) */
#define WSCALE    0.08838834764831845f   /* 1/sqrt(128) */

__device__ __forceinline__ unsigned short f2bf(float f) {
    union { float f; unsigned int u; } v; v.f = f;
    unsigned int r = v.u + 0x7fffu + ((v.u >> 16) & 1u);
    return (unsigned short)(r >> 16);
}

__device__ __forceinline__ ushort8 pack8(f32x4 a, f32x4 b) {
    ushort8 o;
    o[0] = f2bf(a.x); o[1] = f2bf(a.y); o[2] = f2bf(a.z); o[3] = f2bf(a.w);
    o[4] = f2bf(b.x); o[5] = f2bf(b.y); o[6] = f2bf(b.z); o[7] = f2bf(b.w);
    return o;
}

// ---- Kernel: w_emb (128 x 3072) -> Bt, bank-swizzled bf16 layout.
// Element (n = 16t+col, k = kb*32+quad*8+j) lives at element index
//   t*2048 + (col*16 + ((kb*4+quad) ^ (col&7)))*8 + j
// so the LDS identity-image of a tile gives conflict-free ds_read_b128.
__global__ void k_wt(const float* __restrict__ w_emb, unsigned short* __restrict__ Bt) {
    int o = blockIdx.x * 256 + threadIdx.x;
    if (o >= 3072 * 128) return;
    int t = o >> 11;            // tile (2048 elements)
    int m = (o >> 3) & 255;     // 16B chunk within tile
    int j = o & 7;
    int col = m >> 4;
    int v = (m & 15) ^ (col & 7);
    int kb = v >> 2, quad = v & 3;
    int k = kb * 32 + quad * 8 + j;
    int n = t * 16 + col;
    Bt[o] = f2bf(w_emb[k * 3072 + n] * WSCALE);
}

// ---- Kernel: per-edge prep: emb bf16 [E][128], rT fp32 [128][E], cnt
__global__ void k_prep(const float* __restrict__ x, const float* __restrict__ edge_attr,
                       const float* __restrict__ Yij, const int* __restrict__ edge_index,
                       unsigned short* __restrict__ emb, float* __restrict__ rT,
                       float* __restrict__ cnt) {
    int e = blockIdx.x * 256 + threadIdx.x;
    if (e >= E_EDGES) return;
    int dst = edge_index[e];
    int src = edge_index[E_EDGES + e];
    f32x4 y = *(const f32x4*)(Yij + 4 * (long)e);
    float y0 = y.x, y1a = y.y, y1b = y.z, y1c = y.w;
    const float* xd = x + (long)dst * 80;
    const float* xs = x + (long)src * 80;
    const float* ea = edge_attr + (long)e * 64;

    ushort8* embp = (ushort8*)(emb + (long)e * 128);

    float xsv[80];
#pragma unroll
    for (int i = 0; i < 80; i += 4) {
        f32x4 v = *(const f32x4*)(xs + i);
        xsv[i] = v.x; xsv[i + 1] = v.y; xsv[i + 2] = v.z; xsv[i + 3] = v.w;
    }
#pragma unroll
    for (int cb = 0; cb < 4; ++cb) {
        f32x4 a = *(const f32x4*)(xd + cb * 8);
        f32x4 b = *(const f32x4*)(xd + cb * 8 + 4);
        embp[cb] = pack8(a, b);
    }
#pragma unroll
    for (int cb = 0; cb < 4; ++cb) {
        f32x4 a, b;
        a.x = xsv[cb * 8 + 0]; a.y = xsv[cb * 8 + 1]; a.z = xsv[cb * 8 + 2]; a.w = xsv[cb * 8 + 3];
        b.x = xsv[cb * 8 + 4]; b.y = xsv[cb * 8 + 5]; b.z = xsv[cb * 8 + 6]; b.w = xsv[cb * 8 + 7];
        embp[4 + cb] = pack8(a, b);
    }
#pragma unroll
    for (int cb = 0; cb < 8; ++cb) {
        f32x4 a = *(const f32x4*)(ea + cb * 8);
        f32x4 b = *(const f32x4*)(ea + cb * 8 + 4);
        embp[8 + cb] = pack8(a, b);
    }
#pragma unroll
    for (int u = 0; u < 32; ++u) rT[(long)u * E_EDGES + e] = xsv[u] * y0;
#pragma unroll
    for (int u = 0; u < 16; ++u)
        rT[(long)(32 + u) * E_EDGES + e] =
            (xsv[32 + 3 * u] * y1a + xsv[33 + 3 * u] * y1b + xsv[34 + 3 * u] * y1c) * INV_SQRT3;
#pragma unroll
    for (int u = 0; u < 32; ++u) rT[(long)(48 + u) * E_EDGES + e] = xsv[u];
#pragma unroll
    for (int j = 0; j < 48; ++j) rT[(long)(80 + j) * E_EDGES + e] = xsv[32 + j] * y0;
    atomicAdd(cnt + dst, 1.0f);
}

// ---- Kernel: fused GEMM + u-contraction, Bt staged via LDS double-buffer.
// Block = 2 waves = 64 edges. 1875 blocks exactly, so no wave skips barriers.
__global__ __launch_bounds__(128) void k_gemm(
    const unsigned short* __restrict__ emb, const unsigned short* __restrict__ Bt,
    const float* __restrict__ rT, const int* __restrict__ edge_index,
    const float* __restrict__ Yij, float* __restrict__ summed) {
    const int lane = threadIdx.x & 63;
    const int wave = threadIdx.x >> 6;
    const long e0 = (long)blockIdx.x * 64 + wave * 32;   // 32 edges per wave
    const int col = lane & 15, quad = lane >> 4;

    __shared__ __align__(16) char lds[2][16384];   // 2 x (4 tiles x 4KB)

    // A fragments, register-resident for the whole sweep (2 slabs x 4 k-blocks)
    bfrag A[2][4];
#pragma unroll
    for (int s = 0; s < 2; ++s) {
        const unsigned short* ap = emb + (e0 + s * 16 + col) * 128 + quad * 8;
#pragma unroll
        for (int kb = 0; kb < 4; ++kb) A[s][kb] = *(const bfrag*)(ap + kb * 32);
    }

    // swizzled per-lane B-frag byte offsets within a 4KB tile (constant all tiles)
    const int c7 = col & 7;
    const int o0 = (col * 16 + ((0 + quad) ^ c7)) * 16;
    const int o1 = (col * 16 + ((4 + quad) ^ c7)) * 16;
    const int o2 = (col * 16 + ((8 + quad) ^ c7)) * 16;
    const int o3 = (col * 16 + ((12 + quad) ^ c7)) * 16;

    auto stage = [&](int ci) {
        const char* g = (const char*)Bt + (size_t)ci * 16384 + wave * 8192 + lane * 16;
        char* l = &lds[ci & 1][wave * 8192];
#pragma unroll
        for (int j = 0; j < 8; ++j)
            __builtin_amdgcn_global_load_lds(
                (const __attribute__((address_space(1))) unsigned int*)(g + j * 1024),
                (__attribute__((address_space(3))) unsigned int*)(l + j * 1024), 16, 0, 0);
    };

    f32x4 z = {0.f, 0.f, 0.f, 0.f};
    f32x4 acc_s0[2] = {z, z}, acc_s1[2] = {z, z}, acc_g[2] = {z, z}, acc_t5[2] = {z, z};
    f32x4 acc_v[2][3] = {{z, z, z}, {z, z, z}};

    const float* rbase = rT + e0 + quad * 4;

    auto tile = [&](const char* lt, f32x4& c0, f32x4& c1) {
        bfrag B0 = *(const bfrag*)(lt + o0);
        bfrag B1 = *(const bfrag*)(lt + o1);
        bfrag B2 = *(const bfrag*)(lt + o2);
        bfrag B3 = *(const bfrag*)(lt + o3);
        c0 = z; c1 = z;
        c0 = __builtin_amdgcn_mfma_f32_16x16x32_bf16(A[0][0], B0, c0, 0, 0, 0);
        c1 = __builtin_amdgcn_mfma_f32_16x16x32_bf16(A[1][0], B0, c1, 0, 0, 0);
        c0 = __builtin_amdgcn_mfma_f32_16x16x32_bf16(A[0][1], B1, c0, 0, 0, 0);
        c1 = __builtin_amdgcn_mfma_f32_16x16x32_bf16(A[1][1], B1, c1, 0, 0, 0);
        c0 = __builtin_amdgcn_mfma_f32_16x16x32_bf16(A[0][2], B2, c0, 0, 0, 0);
        c1 = __builtin_amdgcn_mfma_f32_16x16x32_bf16(A[1][2], B2, c1, 0, 0, 0);
        c0 = __builtin_amdgcn_mfma_f32_16x16x32_bf16(A[0][3], B3, c0, 0, 0, 0);
        c1 = __builtin_amdgcn_mfma_f32_16x16x32_bf16(A[1][3], B3, c1, 0, 0, 0);
    };

    stage(0);
    int cidx = 0;
    auto nextbuf = [&]() -> const char* {
        __syncthreads();                    // publishes buf[cidx&1]; frees buf[other]
        if (cidx + 1 < 48) stage(cidx + 1); // async into the other buffer
        const char* b = lds[cidx & 1];
        ++cidx;
        return b;
    };

    f32x4 c0, c1;
    // W1: chunks 0..15, rows 2j,2j+1 -> acc_s
    for (int j = 0; j < 16; ++j) {
        const char* buf = nextbuf();
        const float* r0 = rbase + (long)(2 * j) * E_EDGES;
        const float* r1 = rbase + (long)(2 * j + 1) * E_EDGES;
        f32x4 w00 = *(const f32x4*)(r0), w01 = *(const f32x4*)(r0 + 16);
        f32x4 w10 = *(const f32x4*)(r1), w11 = *(const f32x4*)(r1 + 16);
        tile(buf,        c0, c1); acc_s0[0] += c0 * w00; acc_s0[1] += c1 * w01;
        tile(buf + 4096, c0, c1); acc_s1[0] += c0 * w00; acc_s1[1] += c1 * w01;
        tile(buf + 8192, c0, c1); acc_s0[0] += c0 * w10; acc_s0[1] += c1 * w11;
        tile(buf + 12288,c0, c1); acc_s1[0] += c0 * w10; acc_s1[1] += c1 * w11;
    }
    // W2: chunks 16..23, rows 4j..4j+3 -> acc_g
    for (int j = 0; j < 8; ++j) {
        const char* buf = nextbuf();
#pragma unroll
        for (int i = 0; i < 4; ++i) {
            const float* rw = rbase + (long)(4 * j + i) * E_EDGES;
            f32x4 w0 = *(const f32x4*)(rw), w1 = *(const f32x4*)(rw + 16);
            tile(buf + i * 4096, c0, c1);
            acc_g[0] += c0 * w0; acc_g[1] += c1 * w1;
        }
    }
    // W3: chunks 24..31, rows 32+2j, 32+2j+1 -> acc_s
    for (int j = 0; j < 8; ++j) {
        const char* buf = nextbuf();
        const float* r0 = rbase + (long)(32 + 2 * j) * E_EDGES;
        const float* r1 = rbase + (long)(33 + 2 * j) * E_EDGES;
        f32x4 w00 = *(const f32x4*)(r0), w01 = *(const f32x4*)(r0 + 16);
        f32x4 w10 = *(const f32x4*)(r1), w11 = *(const f32x4*)(r1 + 16);
        tile(buf,        c0, c1); acc_s0[0] += c0 * w00; acc_s0[1] += c1 * w01;
        tile(buf + 4096, c0, c1); acc_s1[0] += c0 * w00; acc_s1[1] += c1 * w01;
        tile(buf + 8192, c0, c1); acc_s0[0] += c0 * w10; acc_s0[1] += c1 * w11;
        tile(buf + 12288,c0, c1); acc_s1[0] += c0 * w10; acc_s1[1] += c1 * w11;
    }
    // W4: chunks 32..35, rows 32+16j.. wait: rows 32+4j+i -> acc_g (u = 4j+i over 0..15)
    for (int j = 0; j < 4; ++j) {
        const char* buf = nextbuf();
#pragma unroll
        for (int i = 0; i < 4; ++i) {
            const float* rw = rbase + (long)(32 + 4 * j + i) * E_EDGES;
            f32x4 w0 = *(const f32x4*)(rw), w1 = *(const f32x4*)(rw + 16);
            tile(buf + i * 4096, c0, c1);
            acc_g[0] += c0 * w0; acc_g[1] += c1 * w1;
        }
    }
    // W5: chunks 36..43, rows 48+4j+i -> acc_t5
    for (int j = 0; j < 8; ++j) {
        const char* buf = nextbuf();
#pragma unroll
        for (int i = 0; i < 4; ++i) {
            const float* rw = rbase + (long)(48 + 4 * j + i) * E_EDGES;
            f32x4 w0 = *(const f32x4*)(rw), w1 = *(const f32x4*)(rw + 16);
            tile(buf + i * 4096, c0, c1);
            acc_t5[0] += c0 * w0; acc_t5[1] += c1 * w1;
        }
    }
    // W6: chunks 44..47, u = 4j+i, rows 80+3u+k -> acc_v[k]
    for (int j = 0; j < 4; ++j) {
        const char* buf = nextbuf();
#pragma unroll
        for (int i = 0; i < 4; ++i) {
            const float* rw = rbase + (long)(80 + 3 * (4 * j + i)) * E_EDGES;
            tile(buf + i * 4096, c0, c1);
#pragma unroll
            for (int k = 0; k < 3; ++k) {
                f32x4 w0 = *(const f32x4*)(rw + (long)k * E_EDGES);
                f32x4 w1 = *(const f32x4*)(rw + (long)k * E_EDGES + 16);
                acc_v[0][k] += c0 * w0;
                acc_v[1][k] += c1 * w1;
            }
        }
    }

    // Epilogue: scale + atomic scatter into summed[node][96]
#pragma unroll
    for (int s = 0; s < 2; ++s) {
        long eb = e0 + s * 16 + quad * 4;
#pragma unroll
        for (int r = 0; r < 4; ++r) {
            long e = eb + r;
            int d = edge_index[e];
            float* base = summed + (long)d * 96;
            float y1a = Yij[4 * e + 1], y1b = Yij[4 * e + 2], y1c = Yij[4 * e + 3];
            atomicAdd(base + col,       N_0E_C * acc_s0[s][r]);
            atomicAdd(base + col + 16,  N_0E_C * acc_s1[s][r]);
            atomicAdd(base + 32 + col,  N_0E_C * acc_g[s][r]);
            float t5 = acc_t5[s][r];
            atomicAdd(base + 48 + col * 3 + 0, NV_C * (t5 * y1a + acc_v[s][0][r]));
            atomicAdd(base + 48 + col * 3 + 1, NV_C * (t5 * y1b + acc_v[s][1][r]));
            atomicAdd(base + 48 + col * 3 + 2, NV_C * (t5 * y1c + acc_v[s][2][r]));
        }
    }
}

// ---- Kernel: mean, relu-gate, residual
__global__ void k_final(const float* __restrict__ x, const float* __restrict__ summed,
                        const float* __restrict__ cnt, float* __restrict__ out) {
    int tid = blockIdx.x * 256 + threadIdx.x;
    if (tid >= NUM_NODES * 80) return;
    int n = tid / 80, c = tid % 80;
    float m = fmaxf(cnt[n], 1.0f);
    float inv = 1.0f / m;
    float val;
    if (c < 32) {
        val = SQRT2_C * fmaxf(summed[(long)n * 96 + c] * inv, 0.0f);
    } else {
        int j = c - 32;
        int w = j / 3;
        float g = SQRT2_C * fmaxf(summed[(long)n * 96 + 32 + w] * inv, 0.0f);
        val = summed[(long)n * 96 + 48 + j] * inv * g;
    }
    out[tid] = x[tid] + val;
}

extern "C" void kernel_launch(void* const* d_in, const int* in_sizes, int n_in,
                              void* d_out, int out_size, void* d_ws, size_t ws_size,
                              hipStream_t stream) {
    const float* x         = (const float*)d_in[0];
    const float* edge_attr = (const float*)d_in[1];
    const float* Yij       = (const float*)d_in[2];
    const int*   edge_index= (const int*)d_in[3];
    const float* w_emb     = (const float*)d_in[4];
    float* out = (float*)d_out;

    char* ws = (char*)d_ws;
    size_t off = 0;
    unsigned short* emb = (unsigned short*)(ws + off); off += (size_t)E_EDGES * 128 * 2;
    unsigned short* Bt  = (unsigned short*)(ws + off); off += (size_t)3072 * 128 * 2;
    off = (off + 255) & ~(size_t)255;
    float* rT     = (float*)(ws + off); off += (size_t)128 * E_EDGES * 4;
    size_t zoff = off;
    float* summed = (float*)(ws + off); off += (size_t)NUM_NODES * 96 * 4;
    float* cnt    = (float*)(ws + off); off += (size_t)NUM_NODES * 4;

    hipMemsetAsync(ws + zoff, 0, (size_t)NUM_NODES * 97 * 4, stream);
    k_wt  <<<(3072 * 128 + 255) / 256, 256, 0, stream>>>(w_emb, Bt);
    k_prep<<<(E_EDGES + 255) / 256, 256, 0, stream>>>(x, edge_attr, Yij, edge_index, emb, rT, cnt);
    k_gemm<<<E_EDGES / 64, 128, 0, stream>>>(emb, Bt, rT, edge_index, Yij, summed);
    k_final<<<(NUM_NODES * 80 + 255) / 256, 256, 0, stream>>>(x, summed, cnt, out);
}

// Round 3
// 399.441 us; speedup vs baseline: 4.4389x; 4.4389x over previous
//
#include <hip/hip_runtime.h>
#include <hip/hip_bf16.h>

#define E_EDGES 120000
#define NUM_NODES 12000

typedef __attribute__((ext_vector_type(8))) short bfrag;          // 8 bf16
typedef __attribute__((ext_vector_type(8))) unsigned short ushort8;
typedef __attribute__((ext_vector_type(4))) float f32x4;

#define INV_SQRT3 0.57735026918962576f
#define SQRT2_C   1.41421356237309515f
#define N_0E_C    0.14433756729740643f   /* 1/sqrt(48) */
#define NV_C      0.14433756729740643f   /* sqrt(3/48)*1/sqrt(3) = 1/sqrt(48) */
#define WSCALE    0.08838834764831845f   /* 1/sqrt(128) */

__device__ __forceinline__ unsigned short f2bf(float f) {
    union { float f; unsigned int u; } v; v.f = f;
    unsigned int r = v.u + 0x7fffu + ((v.u >> 16) & 1u);
    return (unsigned short)(r >> 16);
}

__device__ __forceinline__ ushort8 pack8(f32x4 a, f32x4 b) {
    ushort8 o;
    o[0] = f2bf(a.x); o[1] = f2bf(a.y); o[2] = f2bf(a.z); o[3] = f2bf(a.w);
    o[4] = f2bf(b.x); o[5] = f2bf(b.y); o[6] = f2bf(b.z); o[7] = f2bf(b.w);
    return o;
}

// ---- Kernel: w_emb (128 x 3072) -> Bt, bank-swizzled bf16 layout.
// Element (n = 16t+col, k = kb*32+quad*8+j) at index
//   t*2048 + (col*16 + ((kb*4+quad) ^ (col&7)))*8 + j
__global__ void k_wt(const float* __restrict__ w_emb, unsigned short* __restrict__ Bt) {
    int o = blockIdx.x * 256 + threadIdx.x;
    if (o >= 3072 * 128) return;
    int t = o >> 11;
    int m = (o >> 3) & 255;
    int j = o & 7;
    int col = m >> 4;
    int v = (m & 15) ^ (col & 7);
    int kb = v >> 2, quad = v & 3;
    int k = kb * 32 + quad * 8 + j;
    int n = t * 16 + col;
    Bt[o] = f2bf(w_emb[k * 3072 + n] * WSCALE);
}

// ---- Kernel: per-edge prep: emb bf16 [E][128], rT fp32 [128][E], cnt
__global__ void k_prep(const float* __restrict__ x, const float* __restrict__ edge_attr,
                       const float* __restrict__ Yij, const int* __restrict__ edge_index,
                       unsigned short* __restrict__ emb, float* __restrict__ rT,
                       float* __restrict__ cnt) {
    int e = blockIdx.x * 256 + threadIdx.x;
    if (e >= E_EDGES) return;
    int dst = edge_index[e];
    int src = edge_index[E_EDGES + e];
    f32x4 y = *(const f32x4*)(Yij + 4 * (long)e);
    float y0 = y.x, y1a = y.y, y1b = y.z, y1c = y.w;
    const float* xd = x + (long)dst * 80;
    const float* xs = x + (long)src * 80;
    const float* ea = edge_attr + (long)e * 64;

    ushort8* embp = (ushort8*)(emb + (long)e * 128);

    float xsv[80];
#pragma unroll
    for (int i = 0; i < 80; i += 4) {
        f32x4 v = *(const f32x4*)(xs + i);
        xsv[i] = v.x; xsv[i + 1] = v.y; xsv[i + 2] = v.z; xsv[i + 3] = v.w;
    }
#pragma unroll
    for (int cb = 0; cb < 4; ++cb) {
        f32x4 a = *(const f32x4*)(xd + cb * 8);
        f32x4 b = *(const f32x4*)(xd + cb * 8 + 4);
        embp[cb] = pack8(a, b);
    }
#pragma unroll
    for (int cb = 0; cb < 4; ++cb) {
        f32x4 a, b;
        a.x = xsv[cb * 8 + 0]; a.y = xsv[cb * 8 + 1]; a.z = xsv[cb * 8 + 2]; a.w = xsv[cb * 8 + 3];
        b.x = xsv[cb * 8 + 4]; b.y = xsv[cb * 8 + 5]; b.z = xsv[cb * 8 + 6]; b.w = xsv[cb * 8 + 7];
        embp[4 + cb] = pack8(a, b);
    }
#pragma unroll
    for (int cb = 0; cb < 8; ++cb) {
        f32x4 a = *(const f32x4*)(ea + cb * 8);
        f32x4 b = *(const f32x4*)(ea + cb * 8 + 4);
        embp[8 + cb] = pack8(a, b);
    }
#pragma unroll
    for (int u = 0; u < 32; ++u) rT[(long)u * E_EDGES + e] = xsv[u] * y0;
#pragma unroll
    for (int u = 0; u < 16; ++u)
        rT[(long)(32 + u) * E_EDGES + e] =
            (xsv[32 + 3 * u] * y1a + xsv[33 + 3 * u] * y1b + xsv[34 + 3 * u] * y1c) * INV_SQRT3;
#pragma unroll
    for (int u = 0; u < 32; ++u) rT[(long)(48 + u) * E_EDGES + e] = xsv[u];
#pragma unroll
    for (int j = 0; j < 48; ++j) rT[(long)(80 + j) * E_EDGES + e] = xsv[32 + j] * y0;
    atomicAdd(cnt + dst, 1.0f);
}

// ---- Kernel: fused GEMM + u-contraction; Bt via LDS double-buffer DMA.
// Block = 4 waves = 128 edges; 938 blocks (last block: waves 2,3 duplicate
// edges 119968..119999 and skip the epilogue, so all waves hit all barriers).
__global__ __launch_bounds__(256) void k_gemm(
    const unsigned short* __restrict__ emb, const unsigned short* __restrict__ Bt,
    const float* __restrict__ rT, const int* __restrict__ edge_index,
    const float* __restrict__ Yij, float* __restrict__ summed) {
    const int lane = threadIdx.x & 63;
    const int wave = threadIdx.x >> 6;
    long e0 = (long)blockIdx.x * 128 + (long)wave * 32;
    const bool dup = (e0 + 32 > E_EDGES);
    if (dup) e0 = E_EDGES - 32;
    const int col = lane & 15, quad = lane >> 4;

    __shared__ __align__(16) char lds[2][16384];

    // A fragments, register-resident for the whole sweep
    bfrag A[2][4];
#pragma unroll
    for (int s = 0; s < 2; ++s) {
        const unsigned short* ap = emb + (e0 + s * 16 + col) * 128 + quad * 8;
#pragma unroll
        for (int kb = 0; kb < 4; ++kb) A[s][kb] = *(const bfrag*)(ap + kb * 32);
    }

    const int c7 = col & 7;
    const int o0 = (col * 16 + ((0 + quad) ^ c7)) * 16;
    const int o1 = (col * 16 + ((4 + quad) ^ c7)) * 16;
    const int o2 = (col * 16 + ((8 + quad) ^ c7)) * 16;
    const int o3 = (col * 16 + ((12 + quad) ^ c7)) * 16;

    auto stage = [&](int ci) {
        const char* g = (const char*)Bt + (size_t)ci * 16384 + wave * 4096 + lane * 16;
        char* l = &lds[ci & 1][wave * 4096];
#pragma unroll
        for (int j = 0; j < 4; ++j)
            __builtin_amdgcn_global_load_lds(
                (const __attribute__((address_space(1))) unsigned int*)(g + j * 1024),
                (__attribute__((address_space(3))) unsigned int*)(l + j * 1024), 16, 0, 0);
    };

    f32x4 z = {0.f, 0.f, 0.f, 0.f};
    f32x4 acc_s0[2] = {z, z}, acc_s1[2] = {z, z}, acc_g[2] = {z, z}, acc_t5[2] = {z, z};
    f32x4 acc_v[2][3] = {{z, z, z}, {z, z, z}};

    const float* rbase = rT + e0 + quad * 4;
    auto loadw = [&](int r, f32x4& a, f32x4& b) {
        const float* p = rbase + (long)r * E_EDGES;
        a = *(const f32x4*)(p);
        b = *(const f32x4*)(p + 16);
    };

    auto tile = [&](const char* lt, f32x4& c0, f32x4& c1) {
        bfrag B0 = *(const bfrag*)(lt + o0);
        bfrag B1 = *(const bfrag*)(lt + o1);
        bfrag B2 = *(const bfrag*)(lt + o2);
        bfrag B3 = *(const bfrag*)(lt + o3);
        c0 = z; c1 = z;
        c0 = __builtin_amdgcn_mfma_f32_16x16x32_bf16(A[0][0], B0, c0, 0, 0, 0);
        c1 = __builtin_amdgcn_mfma_f32_16x16x32_bf16(A[1][0], B0, c1, 0, 0, 0);
        c0 = __builtin_amdgcn_mfma_f32_16x16x32_bf16(A[0][1], B1, c0, 0, 0, 0);
        c1 = __builtin_amdgcn_mfma_f32_16x16x32_bf16(A[1][1], B1, c1, 0, 0, 0);
        c0 = __builtin_amdgcn_mfma_f32_16x16x32_bf16(A[0][2], B2, c0, 0, 0, 0);
        c1 = __builtin_amdgcn_mfma_f32_16x16x32_bf16(A[1][2], B2, c1, 0, 0, 0);
        c0 = __builtin_amdgcn_mfma_f32_16x16x32_bf16(A[0][3], B3, c0, 0, 0, 0);
        c1 = __builtin_amdgcn_mfma_f32_16x16x32_bf16(A[1][3], B3, c1, 0, 0, 0);
    };

    stage(0);
    int cidx = 0;
    auto nextbuf = [&]() -> const char* {
        __syncthreads();
        if (cidx + 1 < 48) stage(cidx + 1);
        const char* b = lds[cidx & 1];
        ++cidx;
        return b;
    };

    f32x4 c0, c1;

    // W1: chunks 0..15, rows 2j,2j+1 -> acc_s
    {
        f32x4 p0a, p0b, p1a, p1b;
        loadw(0, p0a, p0b); loadw(1, p1a, p1b);
#pragma unroll 1
        for (int j = 0; j < 16; ++j) {
            const char* buf = nextbuf();
            f32x4 w0a = p0a, w0b = p0b, w1a = p1a, w1b = p1b;
            int nr = (j < 15) ? (2 * j + 2) : 0;
            loadw(nr, p0a, p0b); loadw(nr + 1, p1a, p1b);
            tile(buf,         c0, c1); acc_s0[0] += c0 * w0a; acc_s0[1] += c1 * w0b;
            tile(buf + 4096,  c0, c1); acc_s1[0] += c0 * w0a; acc_s1[1] += c1 * w0b;
            tile(buf + 8192,  c0, c1); acc_s0[0] += c0 * w1a; acc_s0[1] += c1 * w1b;
            tile(buf + 12288, c0, c1); acc_s1[0] += c0 * w1a; acc_s1[1] += c1 * w1b;
        }
    }
    // W2: chunks 16..23, rows 4j..4j+3 -> acc_g
    {
        f32x4 pa[4], pb[4];
#pragma unroll
        for (int i = 0; i < 4; ++i) loadw(i, pa[i], pb[i]);
#pragma unroll 1
        for (int j = 0; j < 8; ++j) {
            const char* buf = nextbuf();
            f32x4 wa[4], wb[4];
#pragma unroll
            for (int i = 0; i < 4; ++i) { wa[i] = pa[i]; wb[i] = pb[i]; }
            int nr = (j < 7) ? (4 * j + 4) : 0;
#pragma unroll
            for (int i = 0; i < 4; ++i) loadw(nr + i, pa[i], pb[i]);
#pragma unroll
            for (int i = 0; i < 4; ++i) {
                tile(buf + i * 4096, c0, c1);
                acc_g[0] += c0 * wa[i]; acc_g[1] += c1 * wb[i];
            }
        }
    }
    // W3: chunks 24..31, rows 32+2j,33+2j -> acc_s
    {
        f32x4 p0a, p0b, p1a, p1b;
        loadw(32, p0a, p0b); loadw(33, p1a, p1b);
#pragma unroll 1
        for (int j = 0; j < 8; ++j) {
            const char* buf = nextbuf();
            f32x4 w0a = p0a, w0b = p0b, w1a = p1a, w1b = p1b;
            int nr = (j < 7) ? (32 + 2 * j + 2) : 32;
            loadw(nr, p0a, p0b); loadw(nr + 1, p1a, p1b);
            tile(buf,         c0, c1); acc_s0[0] += c0 * w0a; acc_s0[1] += c1 * w0b;
            tile(buf + 4096,  c0, c1); acc_s1[0] += c0 * w0a; acc_s1[1] += c1 * w0b;
            tile(buf + 8192,  c0, c1); acc_s0[0] += c0 * w1a; acc_s0[1] += c1 * w1b;
            tile(buf + 12288, c0, c1); acc_s1[0] += c0 * w1a; acc_s1[1] += c1 * w1b;
        }
    }
    // W4: chunks 32..35, rows 32+4j+i -> acc_g
    {
        f32x4 pa[4], pb[4];
#pragma unroll
        for (int i = 0; i < 4; ++i) loadw(32 + i, pa[i], pb[i]);
#pragma unroll 1
        for (int j = 0; j < 4; ++j) {
            const char* buf = nextbuf();
            f32x4 wa[4], wb[4];
#pragma unroll
            for (int i = 0; i < 4; ++i) { wa[i] = pa[i]; wb[i] = pb[i]; }
            int nr = (j < 3) ? (32 + 4 * j + 4) : 32;
#pragma unroll
            for (int i = 0; i < 4; ++i) loadw(nr + i, pa[i], pb[i]);
#pragma unroll
            for (int i = 0; i < 4; ++i) {
                tile(buf + i * 4096, c0, c1);
                acc_g[0] += c0 * wa[i]; acc_g[1] += c1 * wb[i];
            }
        }
    }
    // W5: chunks 36..43, rows 48+4j+i -> acc_t5
    {
        f32x4 pa[4], pb[4];
#pragma unroll
        for (int i = 0; i < 4; ++i) loadw(48 + i, pa[i], pb[i]);
#pragma unroll 1
        for (int j = 0; j < 8; ++j) {
            const char* buf = nextbuf();
            f32x4 wa[4], wb[4];
#pragma unroll
            for (int i = 0; i < 4; ++i) { wa[i] = pa[i]; wb[i] = pb[i]; }
            int nr = (j < 7) ? (48 + 4 * j + 4) : 48;
#pragma unroll
            for (int i = 0; i < 4; ++i) loadw(nr + i, pa[i], pb[i]);
#pragma unroll
            for (int i = 0; i < 4; ++i) {
                tile(buf + i * 4096, c0, c1);
                acc_t5[0] += c0 * wa[i]; acc_t5[1] += c1 * wb[i];
            }
        }
    }
    // W6: chunks 44..47, u=4j+i, rows 80+3u+k -> acc_v[k]
    {
        f32x4 va[3], vb[3];
#pragma unroll
        for (int k = 0; k < 3; ++k) loadw(80 + k, va[k], vb[k]);
#pragma unroll 1
        for (int j = 0; j < 4; ++j) {
            const char* buf = nextbuf();
#pragma unroll
            for (int i = 0; i < 4; ++i) {
                f32x4 wa[3], wb[3];
#pragma unroll
                for (int k = 0; k < 3; ++k) { wa[k] = va[k]; wb[k] = vb[k]; }
                int un = 4 * j + i + 1; if (un > 15) un = 0;
#pragma unroll
                for (int k = 0; k < 3; ++k) loadw(80 + 3 * un + k, va[k], vb[k]);
                tile(buf + i * 4096, c0, c1);
#pragma unroll
                for (int k = 0; k < 3; ++k) {
                    acc_v[0][k] += c0 * wa[k];
                    acc_v[1][k] += c1 * wb[k];
                }
            }
        }
    }

    if (dup) return;
    // Epilogue: scale + atomic scatter into summed[node][96]
#pragma unroll
    for (int s = 0; s < 2; ++s) {
        long eb = e0 + s * 16 + quad * 4;
#pragma unroll
        for (int r = 0; r < 4; ++r) {
            long e = eb + r;
            int d = edge_index[e];
            float* base = summed + (long)d * 96;
            float y1a = Yij[4 * e + 1], y1b = Yij[4 * e + 2], y1c = Yij[4 * e + 3];
            atomicAdd(base + col,       N_0E_C * acc_s0[s][r]);
            atomicAdd(base + col + 16,  N_0E_C * acc_s1[s][r]);
            atomicAdd(base + 32 + col,  N_0E_C * acc_g[s][r]);
            float t5 = acc_t5[s][r];
            atomicAdd(base + 48 + col * 3 + 0, NV_C * (t5 * y1a + acc_v[s][0][r]));
            atomicAdd(base + 48 + col * 3 + 1, NV_C * (t5 * y1b + acc_v[s][1][r]));
            atomicAdd(base + 48 + col * 3 + 2, NV_C * (t5 * y1c + acc_v[s][2][r]));
        }
    }
}

// ---- Kernel: mean, relu-gate, residual
__global__ void k_final(const float* __restrict__ x, const float* __restrict__ summed,
                        const float* __restrict__ cnt, float* __restrict__ out) {
    int tid = blockIdx.x * 256 + threadIdx.x;
    if (tid >= NUM_NODES * 80) return;
    int n = tid / 80, c = tid % 80;
    float m = fmaxf(cnt[n], 1.0f);
    float inv = 1.0f / m;
    float val;
    if (c < 32) {
        val = SQRT2_C * fmaxf(summed[(long)n * 96 + c] * inv, 0.0f);
    } else {
        int j = c - 32;
        int w = j / 3;
        float g = SQRT2_C * fmaxf(summed[(long)n * 96 + 32 + w] * inv, 0.0f);
        val = summed[(long)n * 96 + 48 + j] * inv * g;
    }
    out[tid] = x[tid] + val;
}

extern "C" void kernel_launch(void* const* d_in, const int* in_sizes, int n_in,
                              void* d_out, int out_size, void* d_ws, size_t ws_size,
                              hipStream_t stream) {
    const float* x         = (const float*)d_in[0];
    const float* edge_attr = (const float*)d_in[1];
    const float* Yij       = (const float*)d_in[2];
    const int*   edge_index= (const int*)d_in[3];
    const float* w_emb     = (const float*)d_in[4];
    float* out = (float*)d_out;

    char* ws = (char*)d_ws;
    size_t off = 0;
    unsigned short* emb = (unsigned short*)(ws + off); off += (size_t)E_EDGES * 128 * 2;
    unsigned short* Bt  = (unsigned short*)(ws + off); off += (size_t)3072 * 128 * 2;
    off = (off + 255) & ~(size_t)255;
    float* rT     = (float*)(ws + off); off += (size_t)128 * E_EDGES * 4;
    size_t zoff = off;
    float* summed = (float*)(ws + off); off += (size_t)NUM_NODES * 96 * 4;
    float* cnt    = (float*)(ws + off); off += (size_t)NUM_NODES * 4;

    hipMemsetAsync(ws + zoff, 0, (size_t)NUM_NODES * 97 * 4, stream);
    k_wt  <<<(3072 * 128 + 255) / 256, 256, 0, stream>>>(w_emb, Bt);
    k_prep<<<(E_EDGES + 255) / 256, 256, 0, stream>>>(x, edge_attr, Yij, edge_index, emb, rT, cnt);
    k_gemm<<<(E_EDGES + 127) / 128, 256, 0, stream>>>(emb, Bt, rT, edge_index, Yij, summed);
    k_final<<<(NUM_NODES * 80 + 255) / 256, 256, 0, stream>>>(x, summed, cnt, out);
}

// Round 4
// 291.807 us; speedup vs baseline: 6.0762x; 1.3689x over previous
//
#include <hip/hip_runtime.h>
#include <hip/hip_bf16.h>

#define E_EDGES 120000
#define NUM_NODES 12000

typedef __attribute__((ext_vector_type(8))) short bfrag;          // 8 bf16
typedef __attribute__((ext_vector_type(8))) unsigned short ushort8;
typedef __attribute__((ext_vector_type(4))) float f32x4;

#define INV_SQRT3 0.57735026918962576f
#define SQRT2_C   1.41421356237309515f
#define N_0E_C    0.14433756729740643f   /* 1/sqrt(48) */
#define NV_C      0.14433756729740643f   /* sqrt(3/48)*1/sqrt(3) = 1/sqrt(48) */
#define WSCALE    0.08838834764831845f   /* 1/sqrt(128) */

__device__ __forceinline__ unsigned short f2bf(float f) {
    union { float f; unsigned int u; } v; v.f = f;
    unsigned int r = v.u + 0x7fffu + ((v.u >> 16) & 1u);
    return (unsigned short)(r >> 16);
}

__device__ __forceinline__ ushort8 pack8(f32x4 a, f32x4 b) {
    ushort8 o;
    o[0] = f2bf(a.x); o[1] = f2bf(a.y); o[2] = f2bf(a.z); o[3] = f2bf(a.w);
    o[4] = f2bf(b.x); o[5] = f2bf(b.y); o[6] = f2bf(b.z); o[7] = f2bf(b.w);
    return o;
}

// ---- Kernel: w_emb (128 x 3072) -> Bt in fragment-consumption order.
// Tile t (16 n x 128 k = 4 KB). Fragment slot c = kb*64 + quad*16 + col
// (= kb*64 + lane), element j in 0..7. So in k_gemm, instruction kb reads
// lane*16 + kb*1024: 64 lanes cover one contiguous 1024B block -> conflict-free.
__global__ void k_wt(const float* __restrict__ w_emb, unsigned short* __restrict__ Bt) {
    int o = blockIdx.x * 256 + threadIdx.x;
    if (o >= 3072 * 128) return;
    int t = o >> 11;
    int c = (o >> 3) & 255;
    int j = o & 7;
    int kb = c >> 6;
    int quad = (c >> 4) & 3;
    int col = c & 15;
    int k = kb * 32 + quad * 8 + j;
    int n = t * 16 + col;
    Bt[o] = f2bf(w_emb[k * 3072 + n] * WSCALE);
}

// ---- Kernel: per-edge prep: emb bf16 [E][128], rT fp32 [128][E], cnt
__global__ void k_prep(const float* __restrict__ x, const float* __restrict__ edge_attr,
                       const float* __restrict__ Yij, const int* __restrict__ edge_index,
                       unsigned short* __restrict__ emb, float* __restrict__ rT,
                       float* __restrict__ cnt) {
    int e = blockIdx.x * 256 + threadIdx.x;
    if (e >= E_EDGES) return;
    int dst = edge_index[e];
    int src = edge_index[E_EDGES + e];
    f32x4 y = *(const f32x4*)(Yij + 4 * (long)e);
    float y0 = y.x, y1a = y.y, y1b = y.z, y1c = y.w;
    const float* xd = x + (long)dst * 80;
    const float* xs = x + (long)src * 80;
    const float* ea = edge_attr + (long)e * 64;

    ushort8* embp = (ushort8*)(emb + (long)e * 128);

    float xsv[80];
#pragma unroll
    for (int i = 0; i < 80; i += 4) {
        f32x4 v = *(const f32x4*)(xs + i);
        xsv[i] = v.x; xsv[i + 1] = v.y; xsv[i + 2] = v.z; xsv[i + 3] = v.w;
    }
#pragma unroll
    for (int cb = 0; cb < 4; ++cb) {
        f32x4 a = *(const f32x4*)(xd + cb * 8);
        f32x4 b = *(const f32x4*)(xd + cb * 8 + 4);
        embp[cb] = pack8(a, b);
    }
#pragma unroll
    for (int cb = 0; cb < 4; ++cb) {
        f32x4 a, b;
        a.x = xsv[cb * 8 + 0]; a.y = xsv[cb * 8 + 1]; a.z = xsv[cb * 8 + 2]; a.w = xsv[cb * 8 + 3];
        b.x = xsv[cb * 8 + 4]; b.y = xsv[cb * 8 + 5]; b.z = xsv[cb * 8 + 6]; b.w = xsv[cb * 8 + 7];
        embp[4 + cb] = pack8(a, b);
    }
#pragma unroll
    for (int cb = 0; cb < 8; ++cb) {
        f32x4 a = *(const f32x4*)(ea + cb * 8);
        f32x4 b = *(const f32x4*)(ea + cb * 8 + 4);
        embp[8 + cb] = pack8(a, b);
    }
#pragma unroll
    for (int u = 0; u < 32; ++u) rT[(long)u * E_EDGES + e] = xsv[u] * y0;
#pragma unroll
    for (int u = 0; u < 16; ++u)
        rT[(long)(32 + u) * E_EDGES + e] =
            (xsv[32 + 3 * u] * y1a + xsv[33 + 3 * u] * y1b + xsv[34 + 3 * u] * y1c) * INV_SQRT3;
#pragma unroll
    for (int u = 0; u < 32; ++u) rT[(long)(48 + u) * E_EDGES + e] = xsv[u];
#pragma unroll
    for (int j = 0; j < 48; ++j) rT[(long)(80 + j) * E_EDGES + e] = xsv[32 + j] * y0;
    atomicAdd(cnt + dst, 1.0f);
}

// ---- Kernel: fused GEMM + u-contraction; Bt via LDS double-buffer DMA.
// Block = 4 waves = 128 edges; last block's tail waves duplicate edges and
// skip the epilogue so every wave reaches every barrier.
__global__ __launch_bounds__(256, 4) void k_gemm(
    const unsigned short* __restrict__ emb, const unsigned short* __restrict__ Bt,
    const float* __restrict__ rT, const int* __restrict__ edge_index,
    const float* __restrict__ Yij, float* __restrict__ summed) {
    const int lane = threadIdx.x & 63;
    const int wave = threadIdx.x >> 6;
    long e0 = (long)blockIdx.x * 128 + (long)wave * 32;
    const bool dup = (e0 + 32 > E_EDGES);
    if (dup) e0 = E_EDGES - 32;
    const int col = lane & 15, quad = lane >> 4;

    __shared__ __align__(16) char lds[2][16384];

    // A fragments, register-resident for the whole sweep
    bfrag A[2][4];
#pragma unroll
    for (int s = 0; s < 2; ++s) {
        const unsigned short* ap = emb + (e0 + s * 16 + col) * 128 + quad * 8;
#pragma unroll
        for (int kb = 0; kb < 4; ++kb) A[s][kb] = *(const bfrag*)(ap + kb * 32);
    }

    auto stage = [&](int ci) {
        const char* g = (const char*)Bt + (size_t)ci * 16384 + wave * 4096 + lane * 16;
        char* l = &lds[ci & 1][wave * 4096];
#pragma unroll
        for (int j = 0; j < 4; ++j)
            __builtin_amdgcn_global_load_lds(
                (const __attribute__((address_space(1))) unsigned int*)(g + j * 1024),
                (__attribute__((address_space(3))) unsigned int*)(l + j * 1024), 16, 0, 0);
    };

    f32x4 z = {0.f, 0.f, 0.f, 0.f};
    f32x4 acc_s0[2] = {z, z}, acc_s1[2] = {z, z}, acc_g[2] = {z, z}, acc_t5[2] = {z, z};
    f32x4 acc_v[2][3] = {{z, z, z}, {z, z, z}};

    const float* rbase = rT + e0 + quad * 4;
    auto loadw = [&](int r, f32x4& a, f32x4& b) {
        const float* p = rbase + (long)r * E_EDGES;
        a = *(const f32x4*)(p);
        b = *(const f32x4*)(p + 16);
    };

    auto tile = [&](const char* lt, f32x4& c0, f32x4& c1) {
        bfrag B0 = *(const bfrag*)(lt + lane * 16);
        bfrag B1 = *(const bfrag*)(lt + lane * 16 + 1024);
        bfrag B2 = *(const bfrag*)(lt + lane * 16 + 2048);
        bfrag B3 = *(const bfrag*)(lt + lane * 16 + 3072);
        c0 = z; c1 = z;
        c0 = __builtin_amdgcn_mfma_f32_16x16x32_bf16(A[0][0], B0, c0, 0, 0, 0);
        c1 = __builtin_amdgcn_mfma_f32_16x16x32_bf16(A[1][0], B0, c1, 0, 0, 0);
        c0 = __builtin_amdgcn_mfma_f32_16x16x32_bf16(A[0][1], B1, c0, 0, 0, 0);
        c1 = __builtin_amdgcn_mfma_f32_16x16x32_bf16(A[1][1], B1, c1, 0, 0, 0);
        c0 = __builtin_amdgcn_mfma_f32_16x16x32_bf16(A[0][2], B2, c0, 0, 0, 0);
        c1 = __builtin_amdgcn_mfma_f32_16x16x32_bf16(A[1][2], B2, c1, 0, 0, 0);
        c0 = __builtin_amdgcn_mfma_f32_16x16x32_bf16(A[0][3], B3, c0, 0, 0, 0);
        c1 = __builtin_amdgcn_mfma_f32_16x16x32_bf16(A[1][3], B3, c1, 0, 0, 0);
    };

    stage(0);
    int cidx = 0;
    auto nextbuf = [&]() -> const char* {
        __syncthreads();
        if (cidx + 1 < 48) stage(cidx + 1);
        const char* b = lds[cidx & 1];
        ++cidx;
        return b;
    };

    f32x4 c0, c1;

    // W1: chunks 0..15, rows 2j,2j+1 -> acc_s
    {
        f32x4 p0a, p0b, p1a, p1b;
        loadw(0, p0a, p0b); loadw(1, p1a, p1b);
#pragma unroll 1
        for (int j = 0; j < 16; ++j) {
            const char* buf = nextbuf();
            f32x4 w0a = p0a, w0b = p0b, w1a = p1a, w1b = p1b;
            int nr = (j < 15) ? (2 * j + 2) : 0;
            loadw(nr, p0a, p0b); loadw(nr + 1, p1a, p1b);
            tile(buf,         c0, c1); acc_s0[0] += c0 * w0a; acc_s0[1] += c1 * w0b;
            tile(buf + 4096,  c0, c1); acc_s1[0] += c0 * w0a; acc_s1[1] += c1 * w0b;
            tile(buf + 8192,  c0, c1); acc_s0[0] += c0 * w1a; acc_s0[1] += c1 * w1b;
            tile(buf + 12288, c0, c1); acc_s1[0] += c0 * w1a; acc_s1[1] += c1 * w1b;
        }
    }
    // W2: chunks 16..23, rows 4j..4j+3 -> acc_g
    {
        f32x4 pa[4], pb[4];
#pragma unroll
        for (int i = 0; i < 4; ++i) loadw(i, pa[i], pb[i]);
#pragma unroll 1
        for (int j = 0; j < 8; ++j) {
            const char* buf = nextbuf();
            f32x4 wa[4], wb[4];
#pragma unroll
            for (int i = 0; i < 4; ++i) { wa[i] = pa[i]; wb[i] = pb[i]; }
            int nr = (j < 7) ? (4 * j + 4) : 0;
#pragma unroll
            for (int i = 0; i < 4; ++i) loadw(nr + i, pa[i], pb[i]);
#pragma unroll
            for (int i = 0; i < 4; ++i) {
                tile(buf + i * 4096, c0, c1);
                acc_g[0] += c0 * wa[i]; acc_g[1] += c1 * wb[i];
            }
        }
    }
    // W3: chunks 24..31, rows 32+2j,33+2j -> acc_s
    {
        f32x4 p0a, p0b, p1a, p1b;
        loadw(32, p0a, p0b); loadw(33, p1a, p1b);
#pragma unroll 1
        for (int j = 0; j < 8; ++j) {
            const char* buf = nextbuf();
            f32x4 w0a = p0a, w0b = p0b, w1a = p1a, w1b = p1b;
            int nr = (j < 7) ? (32 + 2 * j + 2) : 32;
            loadw(nr, p0a, p0b); loadw(nr + 1, p1a, p1b);
            tile(buf,         c0, c1); acc_s0[0] += c0 * w0a; acc_s0[1] += c1 * w0b;
            tile(buf + 4096,  c0, c1); acc_s1[0] += c0 * w0a; acc_s1[1] += c1 * w0b;
            tile(buf + 8192,  c0, c1); acc_s0[0] += c0 * w1a; acc_s0[1] += c1 * w1b;
            tile(buf + 12288, c0, c1); acc_s1[0] += c0 * w1a; acc_s1[1] += c1 * w1b;
        }
    }
    // W4: chunks 32..35, rows 32+4j+i -> acc_g
    {
        f32x4 pa[4], pb[4];
#pragma unroll
        for (int i = 0; i < 4; ++i) loadw(32 + i, pa[i], pb[i]);
#pragma unroll 1
        for (int j = 0; j < 4; ++j) {
            const char* buf = nextbuf();
            f32x4 wa[4], wb[4];
#pragma unroll
            for (int i = 0; i < 4; ++i) { wa[i] = pa[i]; wb[i] = pb[i]; }
            int nr = (j < 3) ? (32 + 4 * j + 4) : 32;
#pragma unroll
            for (int i = 0; i < 4; ++i) loadw(nr + i, pa[i], pb[i]);
#pragma unroll
            for (int i = 0; i < 4; ++i) {
                tile(buf + i * 4096, c0, c1);
                acc_g[0] += c0 * wa[i]; acc_g[1] += c1 * wb[i];
            }
        }
    }
    // W5: chunks 36..43, rows 48+4j+i -> acc_t5
    {
        f32x4 pa[4], pb[4];
#pragma unroll
        for (int i = 0; i < 4; ++i) loadw(48 + i, pa[i], pb[i]);
#pragma unroll 1
        for (int j = 0; j < 8; ++j) {
            const char* buf = nextbuf();
            f32x4 wa[4], wb[4];
#pragma unroll
            for (int i = 0; i < 4; ++i) { wa[i] = pa[i]; wb[i] = pb[i]; }
            int nr = (j < 7) ? (48 + 4 * j + 4) : 48;
#pragma unroll
            for (int i = 0; i < 4; ++i) loadw(nr + i, pa[i], pb[i]);
#pragma unroll
            for (int i = 0; i < 4; ++i) {
                tile(buf + i * 4096, c0, c1);
                acc_t5[0] += c0 * wa[i]; acc_t5[1] += c1 * wb[i];
            }
        }
    }
    // W6: chunks 44..47, u=4j+i, rows 80+3u+k -> acc_v[k]
    {
        f32x4 va[3], vb[3];
#pragma unroll
        for (int k = 0; k < 3; ++k) loadw(80 + k, va[k], vb[k]);
#pragma unroll 1
        for (int j = 0; j < 4; ++j) {
            const char* buf = nextbuf();
#pragma unroll
            for (int i = 0; i < 4; ++i) {
                f32x4 wa[3], wb[3];
#pragma unroll
                for (int k = 0; k < 3; ++k) { wa[k] = va[k]; wb[k] = vb[k]; }
                int un = 4 * j + i + 1; if (un > 15) un = 0;
#pragma unroll
                for (int k = 0; k < 3; ++k) loadw(80 + 3 * un + k, va[k], vb[k]);
                tile(buf + i * 4096, c0, c1);
#pragma unroll
                for (int k = 0; k < 3; ++k) {
                    acc_v[0][k] += c0 * wa[k];
                    acc_v[1][k] += c1 * wb[k];
                }
            }
        }
    }

    if (dup) return;
    // Epilogue: scale + atomic scatter into summed[node][96]
#pragma unroll
    for (int s = 0; s < 2; ++s) {
        long eb = e0 + s * 16 + quad * 4;
#pragma unroll
        for (int r = 0; r < 4; ++r) {
            long e = eb + r;
            int d = edge_index[e];
            float* base = summed + (long)d * 96;
            float y1a = Yij[4 * e + 1], y1b = Yij[4 * e + 2], y1c = Yij[4 * e + 3];
            atomicAdd(base + col,       N_0E_C * acc_s0[s][r]);
            atomicAdd(base + col + 16,  N_0E_C * acc_s1[s][r]);
            atomicAdd(base + 32 + col,  N_0E_C * acc_g[s][r]);
            float t5 = acc_t5[s][r];
            atomicAdd(base + 48 + col * 3 + 0, NV_C * (t5 * y1a + acc_v[s][0][r]));
            atomicAdd(base + 48 + col * 3 + 1, NV_C * (t5 * y1b + acc_v[s][1][r]));
            atomicAdd(base + 48 + col * 3 + 2, NV_C * (t5 * y1c + acc_v[s][2][r]));
        }
    }
}

// ---- Kernel: mean, relu-gate, residual
__global__ void k_final(const float* __restrict__ x, const float* __restrict__ summed,
                        const float* __restrict__ cnt, float* __restrict__ out) {
    int tid = blockIdx.x * 256 + threadIdx.x;
    if (tid >= NUM_NODES * 80) return;
    int n = tid / 80, c = tid % 80;
    float m = fmaxf(cnt[n], 1.0f);
    float inv = 1.0f / m;
    float val;
    if (c < 32) {
        val = SQRT2_C * fmaxf(summed[(long)n * 96 + c] * inv, 0.0f);
    } else {
        int j = c - 32;
        int w = j / 3;
        float g = SQRT2_C * fmaxf(summed[(long)n * 96 + 32 + w] * inv, 0.0f);
        val = summed[(long)n * 96 + 48 + j] * inv * g;
    }
    out[tid] = x[tid] + val;
}

extern "C" void kernel_launch(void* const* d_in, const int* in_sizes, int n_in,
                              void* d_out, int out_size, void* d_ws, size_t ws_size,
                              hipStream_t stream) {
    const float* x         = (const float*)d_in[0];
    const float* edge_attr = (const float*)d_in[1];
    const float* Yij       = (const float*)d_in[2];
    const int*   edge_index= (const int*)d_in[3];
    const float* w_emb     = (const float*)d_in[4];
    float* out = (float*)d_out;

    char* ws = (char*)d_ws;
    size_t off = 0;
    unsigned short* emb = (unsigned short*)(ws + off); off += (size_t)E_EDGES * 128 * 2;
    unsigned short* Bt  = (unsigned short*)(ws + off); off += (size_t)3072 * 128 * 2;
    off = (off + 255) & ~(size_t)255;
    float* rT     = (float*)(ws + off); off += (size_t)128 * E_EDGES * 4;
    size_t zoff = off;
    float* summed = (float*)(ws + off); off += (size_t)NUM_NODES * 96 * 4;
    float* cnt    = (float*)(ws + off); off += (size_t)NUM_NODES * 4;

    hipMemsetAsync(ws + zoff, 0, (size_t)NUM_NODES * 97 * 4, stream);
    k_wt  <<<(3072 * 128 + 255) / 256, 256, 0, stream>>>(w_emb, Bt);
    k_prep<<<(E_EDGES + 255) / 256, 256, 0, stream>>>(x, edge_attr, Yij, edge_index, emb, rT, cnt);
    k_gemm<<<(E_EDGES + 127) / 128, 256, 0, stream>>>(emb, Bt, rT, edge_index, Yij, summed);
    k_final<<<(NUM_NODES * 80 + 255) / 256, 256, 0, stream>>>(x, summed, cnt, out);
}